// Round 20
// baseline (188.781 us; speedup 1.0000x reference)
//
#include <hip/hip_runtime.h>
#include <hip/hip_bf16.h>

typedef __attribute__((ext_vector_type(8)))  short bf16x8;
typedef __attribute__((ext_vector_type(4)))  float f32x4;
typedef __attribute__((ext_vector_type(16))) float f32x16;
typedef __attribute__((ext_vector_type(2)))  int   i32x2;

#define NH  16
#define HD  64
#define SEQ 2048
#define DM  1024   // NH*HD
#define NB  4

// Q pre-scale: 1/sqrt(64) * log2(e)  (softmax done in exp2 domain)
#define QSCALE 0.18033688011112042f

#define MFMA(a,b,c)   __builtin_amdgcn_mfma_f32_16x16x32_bf16((a),(b),(c),0,0,0)
#define MFMA32(a,b,c) __builtin_amdgcn_mfma_f32_32x32x16_bf16((a),(b),(c),0,0,0)

static __device__ __forceinline__ void gload_lds16(const void* g, void* l) {
    __builtin_amdgcn_global_load_lds(
        (const __attribute__((address_space(1))) void*)g,
        (__attribute__((address_space(3))) void*)l, 16, 0, 0);
}

// ======== fused prep: cast x->bf16 (8/thread) + transpose-cast all weights ========
__global__ __launch_bounds__(256)
void prep(const float* __restrict__ x,  const float* __restrict__ Wq,
          const float* __restrict__ Wk, const float* __restrict__ Wv,
          const float* __restrict__ Wp,
          __hip_bfloat16* __restrict__ xb,  __hip_bfloat16* __restrict__ wqt,
          __hip_bfloat16* __restrict__ wkt, __hip_bfloat16* __restrict__ wvt,
          __hip_bfloat16* __restrict__ wpt) {
    const long XE = (long)NB * SEQ * DM;      // 8,388,608
    const long CAST_T = XE / 8;               // 1,048,576 threads
    long gid = (long)blockIdx.x * 256 + threadIdx.x;
    if (gid < CAST_T) {
        long i = gid * 8;
        float4 a = *reinterpret_cast<const float4*>(x + i);
        float4 b = *reinterpret_cast<const float4*>(x + i + 4);
        ushort4 o1, o2;
        o1.x = __bfloat16_as_ushort(__float2bfloat16(a.x));
        o1.y = __bfloat16_as_ushort(__float2bfloat16(a.y));
        o1.z = __bfloat16_as_ushort(__float2bfloat16(a.z));
        o1.w = __bfloat16_as_ushort(__float2bfloat16(a.w));
        o2.x = __bfloat16_as_ushort(__float2bfloat16(b.x));
        o2.y = __bfloat16_as_ushort(__float2bfloat16(b.y));
        o2.z = __bfloat16_as_ushort(__float2bfloat16(b.z));
        o2.w = __bfloat16_as_ushort(__float2bfloat16(b.w));
        *reinterpret_cast<ushort4*>(xb + i)     = o1;
        *reinterpret_cast<ushort4*>(xb + i + 4) = o2;
        return;
    }
    long r = gid - CAST_T;                    // 0 .. 4M-1
    const long WQK = 1 << 20;                 // NH*DM*HD = 2^20
    if (r < 3 * WQK) {
        int z = (int)(r >> 20);
        long idx = r & (WQK - 1);
        const float* src = (z == 0) ? Wq : (z == 1) ? Wk : Wv;
        __hip_bfloat16* dst = (z == 0) ? wqt : (z == 1) ? wkt : wvt;
        int c  = (int)(idx & 63);             // HD index
        long t2 = idx >> 6;
        int rr = (int)(t2 & 1023);            // D index
        int mm = (int)(t2 >> 10);             // head
        dst[((long)mm * HD + c) * DM + rr] = __float2bfloat16(src[idx]);
    } else {
        long idx = r - 3 * WQK;               // 0..1M-1 over Wp [D][D]
        int c  = (int)(idx & 1023);
        int rr = (int)(idx >> 10);
        wpt[(long)c * DM + rr] = __float2bfloat16(Wp[idx]);
    }
}

// ======== qkv GEMM: 128x128 tile, BK=64, counted-vmcnt pipeline (r18) ========
__global__ __launch_bounds__(256)
void qkv_gemm(const __hip_bfloat16* __restrict__ A,
              const __hip_bfloat16* __restrict__ BT,
              const float* __restrict__ b0,
              const float* __restrict__ b1,
              const float* __restrict__ b2,
              __hip_bfloat16* __restrict__ Qo,
              __hip_bfloat16* __restrict__ Ko,
              __hip_bfloat16* __restrict__ Vto) {
    __shared__ __align__(16) char lds[2][32768];   // [buf][A:0..16383 | B:16384..32767]
    int tid = threadIdx.x;
    int w = tid >> 6, l = tid & 63;
    int lr = l & 15, lg = l >> 4;
    int wr = w >> 1, wc = w & 1;
    int mtile = blockIdx.x, ntile = blockIdx.y;
    const int AR0 = mtile * 128, BR0 = ntile * 128;

    const int rsub = w * 8 + (l >> 3);
    const int sg0 = l & 7;
    auto stage = [&](const __hip_bfloat16* g, int grow0, int kc, char* lbase) {
#pragma unroll
        for (int i = 0; i < 4; ++i) {
            int row = i * 32 + rsub;
            gload_lds16(g + (long)(grow0 + row) * DM + kc + ((sg0 ^ (row & 7)) << 3),
                        lbase + i * 4096 + w * 1024);
        }
    };

    int aoff[4][2], boff[4][2];
#pragma unroll
    for (int m = 0; m < 4; ++m) {
        int ra = wr * 64 + m * 16 + lr;
        int rb = wc * 64 + m * 16 + lr;
#pragma unroll
        for (int kh = 0; kh < 2; ++kh) {
            aoff[m][kh] = ra * 128 + (((kh * 4 + lg) ^ (ra & 7)) << 4);
            boff[m][kh] = 16384 + rb * 128 + (((kh * 4 + lg) ^ (rb & 7)) << 4);
        }
    }

    f32x4 acc[4][4] = {};

    stage(A,  AR0, 0, lds[0]);
    stage(BT, BR0, 0, lds[0] + 16384);

    int cur = 0;
    for (int kt = 0; kt < 16; ++kt) {
        if (kt < 15) {
            int kc = (kt + 1) * 64;
            stage(A,  AR0, kc, lds[cur ^ 1]);
            stage(BT, BR0, kc, lds[cur ^ 1] + 16384);
            __builtin_amdgcn_sched_barrier(0);
            asm volatile("s_waitcnt vmcnt(8)" ::: "memory");
        } else {
            asm volatile("s_waitcnt vmcnt(0)" ::: "memory");
        }
        __builtin_amdgcn_sched_barrier(0);
        __builtin_amdgcn_s_barrier();              // all waves' tile-kt loads landed
        __builtin_amdgcn_sched_barrier(0);

        bf16x8 bf[4][2];
#pragma unroll
        for (int n = 0; n < 4; ++n) {
            bf[n][0] = *(const bf16x8*)(lds[cur] + boff[n][0]);
            bf[n][1] = *(const bf16x8*)(lds[cur] + boff[n][1]);
        }
#pragma unroll
        for (int m = 0; m < 4; ++m) {
            bf16x8 a0 = *(const bf16x8*)(lds[cur] + aoff[m][0]);
            bf16x8 a1 = *(const bf16x8*)(lds[cur] + aoff[m][1]);
#pragma unroll
            for (int n = 0; n < 4; ++n) {
                acc[m][n] = MFMA(a0, bf[n][0], acc[m][n]);
                acc[m][n] = MFMA(a1, bf[n][1], acc[m][n]);
            }
        }
        asm volatile("s_waitcnt lgkmcnt(0)" ::: "memory");
        __builtin_amdgcn_sched_barrier(0);
        __builtin_amdgcn_s_barrier();              // all waves done reading lds[cur]
        __builtin_amdgcn_sched_barrier(0);
        cur ^= 1;
    }

    int z = ntile >> 3;
    const float* bias = (z == 0) ? b0 : (z == 1) ? b1 : b2;
    int colbase = (ntile & 7) * 128 + wc * 64;
#pragma unroll
    for (int n = 0; n < 4; ++n) {
        int hc = colbase + n * 16 + lr;              // h*64+e
        int h = hc >> 6, e = hc & 63;
        float bb = bias[hc];
#pragma unroll
        for (int m = 0; m < 4; ++m) {
            int row0 = mtile * 128 + wr * 64 + m * 16 + lg * 4;
            int b = row0 >> 11, s0 = row0 & 2047;
            if (z == 0) {
#pragma unroll
                for (int r = 0; r < 4; ++r)
                    Qo[(((long)b * NH + h) * SEQ + s0 + r) * HD + e] =
                        __float2bfloat16((acc[m][n][r] + bb) * QSCALE);
            } else if (z == 1) {
#pragma unroll
                for (int r = 0; r < 4; ++r)
                    Ko[(((long)b * NH + h) * SEQ + s0 + r) * HD + e] =
                        __float2bfloat16(acc[m][n][r] + bb);
            } else {
                ushort4 s4;
                s4.x = __bfloat16_as_ushort(__float2bfloat16(acc[m][n][0] + bb));
                s4.y = __bfloat16_as_ushort(__float2bfloat16(acc[m][n][1] + bb));
                s4.z = __bfloat16_as_ushort(__float2bfloat16(acc[m][n][2] + bb));
                s4.w = __bfloat16_as_ushort(__float2bfloat16(acc[m][n][3] + bb));
                *reinterpret_cast<ushort4*>(
                    Vto + ((long)(b * NH + h) * HD + e) * SEQ + s0) = s4;
            }
        }
    }
}

// ---- out projection GEMM: 128x128, BK=64, counted-vmcnt (same scheme) ----
__global__ __launch_bounds__(256)
void out_gemm(const __hip_bfloat16* __restrict__ A,
              const __hip_bfloat16* __restrict__ BT,
              const float* __restrict__ b0,
              float* __restrict__ Fo) {
    __shared__ __align__(16) char lds[2][32768];
    int tid = threadIdx.x;
    int w = tid >> 6, l = tid & 63;
    int lr = l & 15, lg = l >> 4;
    int wr = w >> 1, wc = w & 1;
    int mtile = blockIdx.x, ntile = blockIdx.y;
    const int AR0 = mtile * 128, BR0 = ntile * 128;

    const int rsub = w * 8 + (l >> 3);
    const int sg0 = l & 7;
    auto stage = [&](const __hip_bfloat16* g, int grow0, int kc, char* lbase) {
#pragma unroll
        for (int i = 0; i < 4; ++i) {
            int row = i * 32 + rsub;
            gload_lds16(g + (long)(grow0 + row) * DM + kc + ((sg0 ^ (row & 7)) << 3),
                        lbase + i * 4096 + w * 1024);
        }
    };

    int aoff[4][2], boff[4][2];
#pragma unroll
    for (int m = 0; m < 4; ++m) {
        int ra = wr * 64 + m * 16 + lr;
        int rb = wc * 64 + m * 16 + lr;
#pragma unroll
        for (int kh = 0; kh < 2; ++kh) {
            aoff[m][kh] = ra * 128 + (((kh * 4 + lg) ^ (ra & 7)) << 4);
            boff[m][kh] = 16384 + rb * 128 + (((kh * 4 + lg) ^ (rb & 7)) << 4);
        }
    }

    f32x4 acc[4][4] = {};

    stage(A,  AR0, 0, lds[0]);
    stage(BT, BR0, 0, lds[0] + 16384);

    int cur = 0;
    for (int kt = 0; kt < 16; ++kt) {
        if (kt < 15) {
            int kc = (kt + 1) * 64;
            stage(A,  AR0, kc, lds[cur ^ 1]);
            stage(BT, BR0, kc, lds[cur ^ 1] + 16384);
            __builtin_amdgcn_sched_barrier(0);
            asm volatile("s_waitcnt vmcnt(8)" ::: "memory");
        } else {
            asm volatile("s_waitcnt vmcnt(0)" ::: "memory");
        }
        __builtin_amdgcn_sched_barrier(0);
        __builtin_amdgcn_s_barrier();
        __builtin_amdgcn_sched_barrier(0);

        bf16x8 bf[4][2];
#pragma unroll
        for (int n = 0; n < 4; ++n) {
            bf[n][0] = *(const bf16x8*)(lds[cur] + boff[n][0]);
            bf[n][1] = *(const bf16x8*)(lds[cur] + boff[n][1]);
        }
#pragma unroll
        for (int m = 0; m < 4; ++m) {
            bf16x8 a0 = *(const bf16x8*)(lds[cur] + aoff[m][0]);
            bf16x8 a1 = *(const bf16x8*)(lds[cur] + aoff[m][1]);
#pragma unroll
            for (int n = 0; n < 4; ++n) {
                acc[m][n] = MFMA(a0, bf[n][0], acc[m][n]);
                acc[m][n] = MFMA(a1, bf[n][1], acc[m][n]);
            }
        }
        asm volatile("s_waitcnt lgkmcnt(0)" ::: "memory");
        __builtin_amdgcn_sched_barrier(0);
        __builtin_amdgcn_s_barrier();
        __builtin_amdgcn_sched_barrier(0);
        cur ^= 1;
    }

#pragma unroll
    for (int n = 0; n < 4; ++n) {
        int col = ntile * 128 + wc * 64 + n * 16 + lr;
        float bb = b0[col];
#pragma unroll
        for (int m = 0; m < 4; ++m) {
            long row0 = mtile * 128 + wr * 64 + m * 16 + lg * 4;
#pragma unroll
            for (int r = 0; r < 4; ++r)
                Fo[(row0 + r) * DM + col] = acc[m][n][r] + bb;
        }
    }
}

// ---------------- helpers for flash ----------------
static __device__ __forceinline__ unsigned pkbf(float a, float b) {
    __hip_bfloat162 h = __float22bfloat162_rn(float2{a, b});  // a -> low 16
    union { __hip_bfloat162 h2; unsigned u; } u_; u_.h2 = h;
    return u_.u;
}
static __device__ __forceinline__ bf16x8 make_pb(unsigned w0, unsigned w1,
                                                 unsigned w2, unsigned w3) {
    union { unsigned u[4]; bf16x8 v; } u_;
    u_.u[0] = w0; u_.u[1] = w1; u_.u[2] = w2; u_.u[3] = w3;
    return u_.v;
}
static __device__ __forceinline__ i32x2 pl32swap(unsigned a, unsigned b) {
    return __builtin_amdgcn_permlane32_swap((int)a, (int)b, false, false);
}
static __device__ __forceinline__ float xsum32(float x) {
    i32x2 r = pl32swap(__float_as_uint(x), __float_as_uint(x));
    return __uint_as_float((unsigned)r[0]) + __uint_as_float((unsigned)r[1]);
}

// One 32-wide kv sub-tile of one chain: QK^T (swapped), NO-MAX softmax (exact:
// plain sums; per-lane half-row lsum, cross-half merge deferred), P->bf16 via
// permlane, PV. vf = {v00, v10, v01, v11}. (unchanged, proven)
template<bool MASKED>
static __device__ __forceinline__ void attn_tile(
    const bf16x8* kf, const bf16x8* qf, const bf16x8* vf,
    int lo5, int hi,
    f32x16& o0, f32x16& o1, float& lsum) {
    f32x16 st = {};
    __builtin_amdgcn_s_setprio(1);
#pragma unroll
    for (int kd = 0; kd < 4; ++kd) st = MFMA32(kf[kd], qf[kd], st);
    __builtin_amdgcn_s_setprio(0);
    if (MASKED) {
#pragma unroll
        for (int r = 0; r < 16; ++r) {
            int kvloc = (r & 3) + 8 * (r >> 2) + 4 * hi;
            st[r] = (kvloc > lo5) ? -INFINITY : st[r];
        }
    }
    float p[16];
#pragma unroll
    for (int r = 0; r < 16; ++r) p[r] = __builtin_amdgcn_exp2f(st[r]);  // exp2(-inf)=0
    float s0 = (p[0] + p[1]) + (p[2] + p[3]);
    float s1 = (p[4] + p[5]) + (p[6] + p[7]);
    float s2 = (p[8] + p[9]) + (p[10] + p[11]);
    float s3 = (p[12] + p[13]) + (p[14] + p[15]);
    lsum += (s0 + s1) + (s2 + s3);            // per-lane half-row partial

    unsigned pk0 = pkbf(p[0],  p[1]),  pk1 = pkbf(p[2],  p[3]);
    unsigned pk2 = pkbf(p[4],  p[5]),  pk3 = pkbf(p[6],  p[7]);
    unsigned pk4 = pkbf(p[8],  p[9]),  pk5 = pkbf(p[10], p[11]);
    unsigned pk6 = pkbf(p[12], p[13]), pk7 = pkbf(p[14], p[15]);
    i32x2 s02 = pl32swap(pk0, pk2);
    i32x2 s13 = pl32swap(pk1, pk3);
    i32x2 s46 = pl32swap(pk4, pk6);
    i32x2 s57 = pl32swap(pk5, pk7);
    bf16x8 pb0 = make_pb((unsigned)s02[0], (unsigned)s13[0],
                         (unsigned)s02[1], (unsigned)s13[1]);
    bf16x8 pb1 = make_pb((unsigned)s46[0], (unsigned)s57[0],
                         (unsigned)s46[1], (unsigned)s57[1]);

    __builtin_amdgcn_s_setprio(1);
    o0 = MFMA32(vf[0], pb0, o0);
    o1 = MFMA32(vf[1], pb0, o1);
    o0 = MFMA32(vf[2], pb1, o0);
    o1 = MFMA32(vf[3], pb1, o1);
    __builtin_amdgcn_s_setprio(0);
}

// ------ flash attention (causal, block-shared LDS K/V, KVBLK=64) ------
// 64-wide kv tiles processed as two in-register 32-sub-tiles per barrier pair:
// half the iterations/barriers/stage-blocks of the r14 structure, same math.
// LDS per buf: K 64x128B (8KB) + V 64x128B (8KB, rows=d, cols=kv slice).
// Granule XOR swizzle g^=(row&7), inverse-applied on global source (rule #21).
// Diagonals by chain parity: j even -> sub0 masked only; j odd -> sub0 full +
// sub1 masked. Counted vmcnt(4) (r18 scheme), raw double barriers.
__global__ __launch_bounds__(256)
void flash_attn(const __hip_bfloat16* __restrict__ Q,
                const __hip_bfloat16* __restrict__ K,
                const __hip_bfloat16* __restrict__ Vt,
                __hip_bfloat16* __restrict__ O) {
    __shared__ __align__(16) char kv[2][16384];   // [buf][K:0..8191 | V:8192..16383]
    int bh = blockIdx.x;
    int w  = threadIdx.x >> 6, l = threadIdx.x & 63;
    int lo5 = l & 31, hi = l >> 5;
    int y  = blockIdx.y;                 // 0..7
    int pr = y * 4 + w;                  // 0..31
    int jA = pr, jB = 63 - pr;
    int uA = jA >> 1, uB = jB >> 1;      // 64-wide tile index of each diagonal
    int q0A = jA * 32, q0B = jB * 32;
    const int TMAX = 31 - 2 * y;         // max uB within block (w=0, jB=63-4y)

    const __hip_bfloat16* Qh = Q  + (long)bh * SEQ * HD;
    const __hip_bfloat16* Kh = K  + (long)bh * SEQ * HD;
    const __hip_bfloat16* Vh = Vt + (long)bh * HD * SEQ;   // [64][2048]

    bf16x8 qfA[4], qfB[4];
#pragma unroll
    for (int kd = 0; kd < 4; ++kd) {
        qfA[kd] = *reinterpret_cast<const bf16x8*>(
            Qh + (long)(q0A + lo5) * HD + kd * 16 + hi * 8);
        qfB[kd] = *reinterpret_cast<const bf16x8*>(
            Qh + (long)(q0B + lo5) * HD + kd * 16 + hi * 8);
    }

    // staging: srl = row-local within 32-row half (0..31); 2 K + 2 V issues/wave.
    const int srl = w * 8 + (l >> 3);
    const int sgl = l & 7;
    const int ksg8 = (sgl ^ (srl & 7)) << 3;      // inverse-swizzled granule (elems)

    // read byte-offsets (swizzle-matched); sub1 row = +32 -> +4096B (same XOR)
    int ka[4];
#pragma unroll
    for (int kd = 0; kd < 4; ++kd)
        ka[kd] = lo5 * 128 + (((kd * 2 + hi) ^ (lo5 & 7)) << 4);
    // V region (8192+): row d in {lo5, 32+lo5}; granule = s*4 + q*2 + hi
    int vb[2][2];
#pragma unroll
    for (int s = 0; s < 2; ++s)
#pragma unroll
        for (int q = 0; q < 2; ++q)
            vb[s][q] = 8192 + lo5 * 128 + (((s * 4 + q * 2 + hi) ^ (lo5 & 7)) << 4);

    f32x16 oA0 = {}, oA1 = {}, oB0 = {}, oB1 = {};
    float lsA = 0.f, lsB = 0.f;

#define STAGE(T, BUFP)                                                        \
    {                                                                         \
        long kv0_ = (long)(T) * 64;                                           \
        gload_lds16(Kh + (kv0_ + srl) * HD + ksg8,        (BUFP) + w * 1024); \
        gload_lds16(Kh + (kv0_ + 32 + srl) * HD + ksg8,   (BUFP) + 4096 + w * 1024); \
        gload_lds16(Vh + (long)srl * SEQ + kv0_ + ksg8,   (BUFP) + 8192 + w * 1024); \
        gload_lds16(Vh + (long)(32 + srl) * SEQ + kv0_ + ksg8,                \
                    (BUFP) + 12288 + w * 1024);                               \
    }

    STAGE(0, kv[0])

    int buf = 0;
    for (int t = 0; t <= TMAX; ++t) {
        if (t < TMAX) {
            STAGE(t + 1, kv[buf ^ 1])
            __builtin_amdgcn_sched_barrier(0);
            asm volatile("s_waitcnt vmcnt(4)" ::: "memory");
        } else {
            asm volatile("s_waitcnt vmcnt(0)" ::: "memory");
        }
        __builtin_amdgcn_sched_barrier(0);
        __builtin_amdgcn_s_barrier();              // all waves' tile-t loads landed
        __builtin_amdgcn_sched_barrier(0);

        if (t <= uB) {
            const char* cb = kv[buf];
            bf16x8 kf0[4], kf1[4], vf0[4], vf1[4];
#pragma unroll
            for (int kd = 0; kd < 4; ++kd) {
                kf0[kd] = *reinterpret_cast<const bf16x8*>(cb + ka[kd]);
                kf1[kd] = *reinterpret_cast<const bf16x8*>(cb + ka[kd] + 4096);
            }
            vf0[0] = *reinterpret_cast<const bf16x8*>(cb + vb[0][0]);
            vf0[1] = *reinterpret_cast<const bf16x8*>(cb + vb[0][0] + 4096);
            vf0[2] = *reinterpret_cast<const bf16x8*>(cb + vb[0][1]);
            vf0[3] = *reinterpret_cast<const bf16x8*>(cb + vb[0][1] + 4096);
            vf1[0] = *reinterpret_cast<const bf16x8*>(cb + vb[1][0]);
            vf1[1] = *reinterpret_cast<const bf16x8*>(cb + vb[1][0] + 4096);
            vf1[2] = *reinterpret_cast<const bf16x8*>(cb + vb[1][1]);
            vf1[3] = *reinterpret_cast<const bf16x8*>(cb + vb[1][1] + 4096);

            if (t < uA) {                          // both chains, both halves
                attn_tile<false>(kf0, qfB, vf0, lo5, hi, oB0, oB1, lsB);
                attn_tile<false>(kf1, qfB, vf1, lo5, hi, oB0, oB1, lsB);
                attn_tile<false>(kf0, qfA, vf0, lo5, hi, oA0, oA1, lsA);
                attn_tile<false>(kf1, qfA, vf1, lo5, hi, oA0, oA1, lsA);
            } else if (t == uA) {                  // A diagonal (parity); B full
                if (jA & 1) {
                    attn_tile<false>(kf0, qfA, vf0, lo5, hi, oA0, oA1, lsA);
                    attn_tile<true >(kf1, qfA, vf1, lo5, hi, oA0, oA1, lsA);
                } else {
                    attn_tile<true >(kf0, qfA, vf0, lo5, hi, oA0, oA1, lsA);
                }
                attn_tile<false>(kf0, qfB, vf0, lo5, hi, oB0, oB1, lsB);
                attn_tile<false>(kf1, qfB, vf1, lo5, hi, oB0, oB1, lsB);
            } else if (t < uB) {                   // B only, both halves
                attn_tile<false>(kf0, qfB, vf0, lo5, hi, oB0, oB1, lsB);
                attn_tile<false>(kf1, qfB, vf1, lo5, hi, oB0, oB1, lsB);
            } else {                               // t == uB: B diagonal (parity)
                if (jB & 1) {
                    attn_tile<false>(kf0, qfB, vf0, lo5, hi, oB0, oB1, lsB);
                    attn_tile<true >(kf1, qfB, vf1, lo5, hi, oB0, oB1, lsB);
                } else {
                    attn_tile<true >(kf0, qfB, vf0, lo5, hi, oB0, oB1, lsB);
                }
            }
        }
        asm volatile("s_waitcnt lgkmcnt(0)" ::: "memory");
        __builtin_amdgcn_sched_barrier(0);
        __builtin_amdgcn_s_barrier();              // all waves done reading kv[buf]
        __builtin_amdgcn_sched_barrier(0);
        buf ^= 1;
    }
#undef STAGE

    int b = bh >> 4, h = bh & 15;
    float invA = 1.0f / xsum32(lsA);
    float invB = 1.0f / xsum32(lsB);
#pragma unroll
    for (int c = 0; c < 2; ++c) {
        int q0 = c ? q0B : q0A;
        const f32x16& o0 = c ? oB0 : oA0;
        const f32x16& o1 = c ? oB1 : oA1;
        float inv = c ? invB : invA;
        __hip_bfloat16* orow = O + ((long)b * SEQ + q0 + lo5) * DM + h * HD;
#pragma unroll
        for (int nd = 0; nd < 2; ++nd) {
#pragma unroll
            for (int rg = 0; rg < 4; ++rg) {
                ushort4 s4;
                float a0 = (nd ? o1[rg * 4 + 0] : o0[rg * 4 + 0]) * inv;
                float a1 = (nd ? o1[rg * 4 + 1] : o0[rg * 4 + 1]) * inv;
                float a2 = (nd ? o1[rg * 4 + 2] : o0[rg * 4 + 2]) * inv;
                float a3 = (nd ? o1[rg * 4 + 3] : o0[rg * 4 + 3]) * inv;
                s4.x = __bfloat16_as_ushort(__float2bfloat16(a0));
                s4.y = __bfloat16_as_ushort(__float2bfloat16(a1));
                s4.z = __bfloat16_as_ushort(__float2bfloat16(a2));
                s4.w = __bfloat16_as_ushort(__float2bfloat16(a3));
                *reinterpret_cast<ushort4*>(orow + nd * 32 + rg * 8 + hi * 4) = s4;
            }
        }
    }
}

extern "C" void kernel_launch(void* const* d_in, const int* in_sizes, int n_in,
                              void* d_out, int out_size, void* d_ws, size_t ws_size,
                              hipStream_t stream) {
    const float* x  = (const float*)d_in[0];
    const float* Wq = (const float*)d_in[1];
    const float* bq = (const float*)d_in[2];
    const float* Wk = (const float*)d_in[3];
    const float* bk = (const float*)d_in[4];
    const float* Wv = (const float*)d_in[5];
    const float* bv = (const float*)d_in[6];
    const float* Wp = (const float*)d_in[7];
    const float* bp = (const float*)d_in[8];
    float* out = (float*)d_out;

    char* ws = (char*)d_ws;
    const long XE = (long)NB * SEQ * DM;                 // 8,388,608
    const long QKV_ELEMS = (long)NB * NH * SEQ * HD;     // 8,388,608
    __hip_bfloat16* xb   = (__hip_bfloat16*)ws; ws += XE * 2;
    __hip_bfloat16* Qws  = (__hip_bfloat16*)ws; ws += QKV_ELEMS * 2;
    __hip_bfloat16* Kws  = (__hip_bfloat16*)ws; ws += QKV_ELEMS * 2;
    __hip_bfloat16* Vtws = (__hip_bfloat16*)ws; ws += QKV_ELEMS * 2;
    __hip_bfloat16* Ows  = (__hip_bfloat16*)ws; ws += QKV_ELEMS * 2;
    __hip_bfloat16* wqt  = (__hip_bfloat16*)ws; ws += (long)NH * DM * HD * 2;
    __hip_bfloat16* wkt  = (__hip_bfloat16*)ws; ws += (long)NH * DM * HD * 2;
    __hip_bfloat16* wvt  = (__hip_bfloat16*)ws; ws += (long)NH * DM * HD * 2;
    __hip_bfloat16* wpt  = (__hip_bfloat16*)ws; ws += (long)DM * DM * 2;

    prep<<<20480, 256, 0, stream>>>(x, Wq, Wk, Wv, Wp, xb, wqt, wkt, wvt, wpt);

    qkv_gemm<<<dim3(64, 24), 256, 0, stream>>>(
        xb, wqt, bq, bk, bv, Qws, Kws, Vtws);

    flash_attn<<<dim3(64, 8), 256, 0, stream>>>(Qws, Kws, Vtws, Ows);

    out_gemm<<<dim3(64, 8), 256, 0, stream>>>(Ows, wpt, bp, out);
}

// Round 21
// 177.078 us; speedup vs baseline: 1.0661x; 1.0661x over previous
//
#include <hip/hip_runtime.h>
#include <hip/hip_bf16.h>

typedef __attribute__((ext_vector_type(8)))  short bf16x8;
typedef __attribute__((ext_vector_type(4)))  float f32x4;
typedef __attribute__((ext_vector_type(16))) float f32x16;
typedef __attribute__((ext_vector_type(2)))  int   i32x2;

#define NH  16
#define HD  64
#define SEQ 2048
#define DM  1024   // NH*HD
#define NB  4

// Q pre-scale: 1/sqrt(64) * log2(e)  (softmax done in exp2 domain)
#define QSCALE 0.18033688011112042f

#define MFMA(a,b,c)   __builtin_amdgcn_mfma_f32_16x16x32_bf16((a),(b),(c),0,0,0)
#define MFMA32(a,b,c) __builtin_amdgcn_mfma_f32_32x32x16_bf16((a),(b),(c),0,0,0)

static __device__ __forceinline__ void gload_lds16(const void* g, void* l) {
    __builtin_amdgcn_global_load_lds(
        (const __attribute__((address_space(1))) void*)g,
        (__attribute__((address_space(3))) void*)l, 16, 0, 0);
}

// ======== fused prep: cast x->bf16 (8/thread) + transpose-cast all weights ========
__global__ __launch_bounds__(256)
void prep(const float* __restrict__ x,  const float* __restrict__ Wq,
          const float* __restrict__ Wk, const float* __restrict__ Wv,
          const float* __restrict__ Wp,
          __hip_bfloat16* __restrict__ xb,  __hip_bfloat16* __restrict__ wqt,
          __hip_bfloat16* __restrict__ wkt, __hip_bfloat16* __restrict__ wvt,
          __hip_bfloat16* __restrict__ wpt) {
    const long XE = (long)NB * SEQ * DM;      // 8,388,608
    const long CAST_T = XE / 8;               // 1,048,576 threads
    long gid = (long)blockIdx.x * 256 + threadIdx.x;
    if (gid < CAST_T) {
        long i = gid * 8;
        float4 a = *reinterpret_cast<const float4*>(x + i);
        float4 b = *reinterpret_cast<const float4*>(x + i + 4);
        ushort4 o1, o2;
        o1.x = __bfloat16_as_ushort(__float2bfloat16(a.x));
        o1.y = __bfloat16_as_ushort(__float2bfloat16(a.y));
        o1.z = __bfloat16_as_ushort(__float2bfloat16(a.z));
        o1.w = __bfloat16_as_ushort(__float2bfloat16(a.w));
        o2.x = __bfloat16_as_ushort(__float2bfloat16(b.x));
        o2.y = __bfloat16_as_ushort(__float2bfloat16(b.y));
        o2.z = __bfloat16_as_ushort(__float2bfloat16(b.z));
        o2.w = __bfloat16_as_ushort(__float2bfloat16(b.w));
        *reinterpret_cast<ushort4*>(xb + i)     = o1;
        *reinterpret_cast<ushort4*>(xb + i + 4) = o2;
        return;
    }
    long r = gid - CAST_T;                    // 0 .. 4M-1
    const long WQK = 1 << 20;                 // NH*DM*HD = 2^20
    if (r < 3 * WQK) {
        int z = (int)(r >> 20);
        long idx = r & (WQK - 1);
        const float* src = (z == 0) ? Wq : (z == 1) ? Wk : Wv;
        __hip_bfloat16* dst = (z == 0) ? wqt : (z == 1) ? wkt : wvt;
        int c  = (int)(idx & 63);             // HD index
        long t2 = idx >> 6;
        int rr = (int)(t2 & 1023);            // D index
        int mm = (int)(t2 >> 10);             // head
        dst[((long)mm * HD + c) * DM + rr] = __float2bfloat16(src[idx]);
    } else {
        long idx = r - 3 * WQK;               // 0..1M-1 over Wp [D][D]
        int c  = (int)(idx & 1023);
        int rr = (int)(idx >> 10);
        wpt[(long)c * DM + rr] = __float2bfloat16(Wp[idx]);
    }
}

// ======== qkv GEMM: 128x128 tile, BK=64, counted-vmcnt pipeline (r18) ========
__global__ __launch_bounds__(256)
void qkv_gemm(const __hip_bfloat16* __restrict__ A,
              const __hip_bfloat16* __restrict__ BT,
              const float* __restrict__ b0,
              const float* __restrict__ b1,
              const float* __restrict__ b2,
              __hip_bfloat16* __restrict__ Qo,
              __hip_bfloat16* __restrict__ Ko,
              __hip_bfloat16* __restrict__ Vto) {
    __shared__ __align__(16) char lds[2][32768];   // [buf][A:0..16383 | B:16384..32767]
    int tid = threadIdx.x;
    int w = tid >> 6, l = tid & 63;
    int lr = l & 15, lg = l >> 4;
    int wr = w >> 1, wc = w & 1;
    int mtile = blockIdx.x, ntile = blockIdx.y;
    const int AR0 = mtile * 128, BR0 = ntile * 128;

    const int rsub = w * 8 + (l >> 3);
    const int sg0 = l & 7;
    auto stage = [&](const __hip_bfloat16* g, int grow0, int kc, char* lbase) {
#pragma unroll
        for (int i = 0; i < 4; ++i) {
            int row = i * 32 + rsub;
            gload_lds16(g + (long)(grow0 + row) * DM + kc + ((sg0 ^ (row & 7)) << 3),
                        lbase + i * 4096 + w * 1024);
        }
    };

    int aoff[4][2], boff[4][2];
#pragma unroll
    for (int m = 0; m < 4; ++m) {
        int ra = wr * 64 + m * 16 + lr;
        int rb = wc * 64 + m * 16 + lr;
#pragma unroll
        for (int kh = 0; kh < 2; ++kh) {
            aoff[m][kh] = ra * 128 + (((kh * 4 + lg) ^ (ra & 7)) << 4);
            boff[m][kh] = 16384 + rb * 128 + (((kh * 4 + lg) ^ (rb & 7)) << 4);
        }
    }

    f32x4 acc[4][4] = {};

    stage(A,  AR0, 0, lds[0]);
    stage(BT, BR0, 0, lds[0] + 16384);

    int cur = 0;
    for (int kt = 0; kt < 16; ++kt) {
        if (kt < 15) {
            int kc = (kt + 1) * 64;
            stage(A,  AR0, kc, lds[cur ^ 1]);
            stage(BT, BR0, kc, lds[cur ^ 1] + 16384);
            __builtin_amdgcn_sched_barrier(0);
            asm volatile("s_waitcnt vmcnt(8)" ::: "memory");
        } else {
            asm volatile("s_waitcnt vmcnt(0)" ::: "memory");
        }
        __builtin_amdgcn_sched_barrier(0);
        __builtin_amdgcn_s_barrier();              // all waves' tile-kt loads landed
        __builtin_amdgcn_sched_barrier(0);

        bf16x8 bf[4][2];
#pragma unroll
        for (int n = 0; n < 4; ++n) {
            bf[n][0] = *(const bf16x8*)(lds[cur] + boff[n][0]);
            bf[n][1] = *(const bf16x8*)(lds[cur] + boff[n][1]);
        }
#pragma unroll
        for (int m = 0; m < 4; ++m) {
            bf16x8 a0 = *(const bf16x8*)(lds[cur] + aoff[m][0]);
            bf16x8 a1 = *(const bf16x8*)(lds[cur] + aoff[m][1]);
#pragma unroll
            for (int n = 0; n < 4; ++n) {
                acc[m][n] = MFMA(a0, bf[n][0], acc[m][n]);
                acc[m][n] = MFMA(a1, bf[n][1], acc[m][n]);
            }
        }
        asm volatile("s_waitcnt lgkmcnt(0)" ::: "memory");
        __builtin_amdgcn_sched_barrier(0);
        __builtin_amdgcn_s_barrier();              // all waves done reading lds[cur]
        __builtin_amdgcn_sched_barrier(0);
        cur ^= 1;
    }

    int z = ntile >> 3;
    const float* bias = (z == 0) ? b0 : (z == 1) ? b1 : b2;
    int colbase = (ntile & 7) * 128 + wc * 64;
#pragma unroll
    for (int n = 0; n < 4; ++n) {
        int hc = colbase + n * 16 + lr;              // h*64+e
        int h = hc >> 6, e = hc & 63;
        float bb = bias[hc];
#pragma unroll
        for (int m = 0; m < 4; ++m) {
            int row0 = mtile * 128 + wr * 64 + m * 16 + lg * 4;
            int b = row0 >> 11, s0 = row0 & 2047;
            if (z == 0) {
#pragma unroll
                for (int r = 0; r < 4; ++r)
                    Qo[(((long)b * NH + h) * SEQ + s0 + r) * HD + e] =
                        __float2bfloat16((acc[m][n][r] + bb) * QSCALE);
            } else if (z == 1) {
#pragma unroll
                for (int r = 0; r < 4; ++r)
                    Ko[(((long)b * NH + h) * SEQ + s0 + r) * HD + e] =
                        __float2bfloat16(acc[m][n][r] + bb);
            } else {
                ushort4 s4;
                s4.x = __bfloat16_as_ushort(__float2bfloat16(acc[m][n][0] + bb));
                s4.y = __bfloat16_as_ushort(__float2bfloat16(acc[m][n][1] + bb));
                s4.z = __bfloat16_as_ushort(__float2bfloat16(acc[m][n][2] + bb));
                s4.w = __bfloat16_as_ushort(__float2bfloat16(acc[m][n][3] + bb));
                *reinterpret_cast<ushort4*>(
                    Vto + ((long)(b * NH + h) * HD + e) * SEQ + s0) = s4;
            }
        }
    }
}

// ---- out projection GEMM: 128x128, BK=64, counted-vmcnt (same scheme) ----
__global__ __launch_bounds__(256)
void out_gemm(const __hip_bfloat16* __restrict__ A,
              const __hip_bfloat16* __restrict__ BT,
              const float* __restrict__ b0,
              float* __restrict__ Fo) {
    __shared__ __align__(16) char lds[2][32768];
    int tid = threadIdx.x;
    int w = tid >> 6, l = tid & 63;
    int lr = l & 15, lg = l >> 4;
    int wr = w >> 1, wc = w & 1;
    int mtile = blockIdx.x, ntile = blockIdx.y;
    const int AR0 = mtile * 128, BR0 = ntile * 128;

    const int rsub = w * 8 + (l >> 3);
    const int sg0 = l & 7;
    auto stage = [&](const __hip_bfloat16* g, int grow0, int kc, char* lbase) {
#pragma unroll
        for (int i = 0; i < 4; ++i) {
            int row = i * 32 + rsub;
            gload_lds16(g + (long)(grow0 + row) * DM + kc + ((sg0 ^ (row & 7)) << 3),
                        lbase + i * 4096 + w * 1024);
        }
    };

    int aoff[4][2], boff[4][2];
#pragma unroll
    for (int m = 0; m < 4; ++m) {
        int ra = wr * 64 + m * 16 + lr;
        int rb = wc * 64 + m * 16 + lr;
#pragma unroll
        for (int kh = 0; kh < 2; ++kh) {
            aoff[m][kh] = ra * 128 + (((kh * 4 + lg) ^ (ra & 7)) << 4);
            boff[m][kh] = 16384 + rb * 128 + (((kh * 4 + lg) ^ (rb & 7)) << 4);
        }
    }

    f32x4 acc[4][4] = {};

    stage(A,  AR0, 0, lds[0]);
    stage(BT, BR0, 0, lds[0] + 16384);

    int cur = 0;
    for (int kt = 0; kt < 16; ++kt) {
        if (kt < 15) {
            int kc = (kt + 1) * 64;
            stage(A,  AR0, kc, lds[cur ^ 1]);
            stage(BT, BR0, kc, lds[cur ^ 1] + 16384);
            __builtin_amdgcn_sched_barrier(0);
            asm volatile("s_waitcnt vmcnt(8)" ::: "memory");
        } else {
            asm volatile("s_waitcnt vmcnt(0)" ::: "memory");
        }
        __builtin_amdgcn_sched_barrier(0);
        __builtin_amdgcn_s_barrier();
        __builtin_amdgcn_sched_barrier(0);

        bf16x8 bf[4][2];
#pragma unroll
        for (int n = 0; n < 4; ++n) {
            bf[n][0] = *(const bf16x8*)(lds[cur] + boff[n][0]);
            bf[n][1] = *(const bf16x8*)(lds[cur] + boff[n][1]);
        }
#pragma unroll
        for (int m = 0; m < 4; ++m) {
            bf16x8 a0 = *(const bf16x8*)(lds[cur] + aoff[m][0]);
            bf16x8 a1 = *(const bf16x8*)(lds[cur] + aoff[m][1]);
#pragma unroll
            for (int n = 0; n < 4; ++n) {
                acc[m][n] = MFMA(a0, bf[n][0], acc[m][n]);
                acc[m][n] = MFMA(a1, bf[n][1], acc[m][n]);
            }
        }
        asm volatile("s_waitcnt lgkmcnt(0)" ::: "memory");
        __builtin_amdgcn_sched_barrier(0);
        __builtin_amdgcn_s_barrier();
        __builtin_amdgcn_sched_barrier(0);
        cur ^= 1;
    }

#pragma unroll
    for (int n = 0; n < 4; ++n) {
        int col = ntile * 128 + wc * 64 + n * 16 + lr;
        float bb = b0[col];
#pragma unroll
        for (int m = 0; m < 4; ++m) {
            long row0 = mtile * 128 + wr * 64 + m * 16 + lg * 4;
#pragma unroll
            for (int r = 0; r < 4; ++r)
                Fo[(row0 + r) * DM + col] = acc[m][n][r] + bb;
        }
    }
}

// ---------------- helpers for flash ----------------
static __device__ __forceinline__ unsigned pkbf(float a, float b) {
    __hip_bfloat162 h = __float22bfloat162_rn(float2{a, b});  // a -> low 16
    union { __hip_bfloat162 h2; unsigned u; } u_; u_.h2 = h;
    return u_.u;
}
static __device__ __forceinline__ bf16x8 make_pb(unsigned w0, unsigned w1,
                                                 unsigned w2, unsigned w3) {
    union { unsigned u[4]; bf16x8 v; } u_;
    u_.u[0] = w0; u_.u[1] = w1; u_.u[2] = w2; u_.u[3] = w3;
    return u_.v;
}
static __device__ __forceinline__ i32x2 pl32swap(unsigned a, unsigned b) {
    return __builtin_amdgcn_permlane32_swap((int)a, (int)b, false, false);
}
static __device__ __forceinline__ float xsum32(float x) {
    i32x2 r = pl32swap(__float_as_uint(x), __float_as_uint(x));
    return __uint_as_float((unsigned)r[0]) + __uint_as_float((unsigned)r[1]);
}

// One kv-tile of one chain: QK^T (swapped), NO-MAX softmax (exact: plain sums;
// per-lane half-row lsum, cross-half merge deferred), P->bf16 via permlane, PV.
template<bool MASKED>
static __device__ __forceinline__ void attn_tile(
    const bf16x8* kf, const bf16x8* qf, const bf16x8* vf,
    int lo5, int hi,
    f32x16& o0, f32x16& o1, float& lsum) {
    f32x16 st = {};
    __builtin_amdgcn_s_setprio(1);
#pragma unroll
    for (int kd = 0; kd < 4; ++kd) st = MFMA32(kf[kd], qf[kd], st);
    __builtin_amdgcn_s_setprio(0);
    if (MASKED) {
#pragma unroll
        for (int r = 0; r < 16; ++r) {
            int kvloc = (r & 3) + 8 * (r >> 2) + 4 * hi;
            st[r] = (kvloc > lo5) ? -INFINITY : st[r];
        }
    }
    float p[16];
#pragma unroll
    for (int r = 0; r < 16; ++r) p[r] = __builtin_amdgcn_exp2f(st[r]);  // exp2(-inf)=0
    float s0 = (p[0] + p[1]) + (p[2] + p[3]);
    float s1 = (p[4] + p[5]) + (p[6] + p[7]);
    float s2 = (p[8] + p[9]) + (p[10] + p[11]);
    float s3 = (p[12] + p[13]) + (p[14] + p[15]);
    lsum += (s0 + s1) + (s2 + s3);            // per-lane half-row partial

    unsigned pk0 = pkbf(p[0],  p[1]),  pk1 = pkbf(p[2],  p[3]);
    unsigned pk2 = pkbf(p[4],  p[5]),  pk3 = pkbf(p[6],  p[7]);
    unsigned pk4 = pkbf(p[8],  p[9]),  pk5 = pkbf(p[10], p[11]);
    unsigned pk6 = pkbf(p[12], p[13]), pk7 = pkbf(p[14], p[15]);
    i32x2 s02 = pl32swap(pk0, pk2);
    i32x2 s13 = pl32swap(pk1, pk3);
    i32x2 s46 = pl32swap(pk4, pk6);
    i32x2 s57 = pl32swap(pk5, pk7);
    bf16x8 pb0 = make_pb((unsigned)s02[0], (unsigned)s13[0],
                         (unsigned)s02[1], (unsigned)s13[1]);
    bf16x8 pb1 = make_pb((unsigned)s46[0], (unsigned)s57[0],
                         (unsigned)s46[1], (unsigned)s57[1]);

    __builtin_amdgcn_s_setprio(1);
    o0 = MFMA32(vf[0], pb0, o0);
    o1 = MFMA32(vf[1], pb0, o1);
    o0 = MFMA32(vf[2], pb1, o0);
    o1 = MFMA32(vf[3], pb1, o1);
    __builtin_amdgcn_s_setprio(0);
}

// ------- flash attention (causal, block-shared LDS K/V, counted-vmcnt) -------
// r14 structure with the r18 barrier scheme (best measured configuration).
__global__ __launch_bounds__(256)
void flash_attn(const __hip_bfloat16* __restrict__ Q,
                const __hip_bfloat16* __restrict__ K,
                const __hip_bfloat16* __restrict__ Vt,
                __hip_bfloat16* __restrict__ O) {
    __shared__ __align__(16) char kv[2][8192];     // [buf][K:0..4095 | V:4096..8191]
    int bh = blockIdx.x;
    int w  = threadIdx.x >> 6, l = threadIdx.x & 63;
    int lo5 = l & 31, hi = l >> 5;
    int y  = blockIdx.y;                 // 0..7
    int pr = y * 4 + w;                  // 0..31
    int jA = pr, jB = 63 - pr;
    int q0A = jA * 32, q0B = jB * 32;
    const int TMAX = 63 - 4 * y;         // max jB within block (w=0)

    const __hip_bfloat16* Qh = Q  + (long)bh * SEQ * HD;
    const __hip_bfloat16* Kh = K  + (long)bh * SEQ * HD;
    const __hip_bfloat16* Vh = Vt + (long)bh * HD * SEQ;   // [64][2048]

    bf16x8 qfA[4], qfB[4];
#pragma unroll
    for (int kd = 0; kd < 4; ++kd) {
        qfA[kd] = *reinterpret_cast<const bf16x8*>(
            Qh + (long)(q0A + lo5) * HD + kd * 16 + hi * 8);
        qfB[kd] = *reinterpret_cast<const bf16x8*>(
            Qh + (long)(q0B + lo5) * HD + kd * 16 + hi * 8);
    }

    int srow = w * 8 + (l >> 3);                       // 0..31
    int kslot = (l & 7) ^ (srow & 7);
    const __hip_bfloat16* ksrc = Kh + (long)srow * HD + kslot * 8;   // + t*32*HD
    int vlog = (l & 7) ^ (srow & 7);
    int vrow = srow + ((vlog >> 2) << 5);
    const __hip_bfloat16* vsrc = Vh + (long)vrow * SEQ + (vlog & 3) * 8;  // + t*32

    int ka[4], va[4];
#pragma unroll
    for (int kd = 0; kd < 4; ++kd)
        ka[kd] = lo5 * 128 + (((kd * 2 + hi) ^ (lo5 & 7)) << 4);
    va[0] = 4096 + lo5 * 128 + (((0 + hi) ^ (lo5 & 7)) << 4);
    va[1] = 4096 + lo5 * 128 + (((4 + hi) ^ (lo5 & 7)) << 4);
    va[2] = 4096 + lo5 * 128 + (((2 + hi) ^ (lo5 & 7)) << 4);
    va[3] = 4096 + lo5 * 128 + (((6 + hi) ^ (lo5 & 7)) << 4);

    f32x16 oA0 = {}, oA1 = {}, oB0 = {}, oB1 = {};
    float lsA = 0.f, lsB = 0.f;

    gload_lds16(ksrc, kv[0] + w * 1024);
    gload_lds16(vsrc, kv[0] + 4096 + w * 1024);

    int buf = 0;
    for (int t = 0; t <= TMAX; ++t) {
        if (t < TMAX) {
            gload_lds16(ksrc + (long)(t + 1) * 32 * HD, kv[buf ^ 1] + w * 1024);
            gload_lds16(vsrc + (t + 1) * 32,            kv[buf ^ 1] + 4096 + w * 1024);
            __builtin_amdgcn_sched_barrier(0);
            asm volatile("s_waitcnt vmcnt(2)" ::: "memory");
        } else {
            asm volatile("s_waitcnt vmcnt(0)" ::: "memory");
        }
        __builtin_amdgcn_sched_barrier(0);
        __builtin_amdgcn_s_barrier();              // all waves' tile-t loads landed
        __builtin_amdgcn_sched_barrier(0);

        const char* cb = kv[buf];
        bf16x8 kf[4], vf[4];
#pragma unroll
        for (int kd = 0; kd < 4; ++kd)
            kf[kd] = *reinterpret_cast<const bf16x8*>(cb + ka[kd]);
#pragma unroll
        for (int j = 0; j < 4; ++j)
            vf[j] = *reinterpret_cast<const bf16x8*>(cb + va[j]);

        if (t < jA) {
            attn_tile<false>(kf, qfB, vf, lo5, hi, oB0, oB1, lsB);
            attn_tile<false>(kf, qfA, vf, lo5, hi, oA0, oA1, lsA);
        } else if (t == jA) {
            attn_tile<true >(kf, qfA, vf, lo5, hi, oA0, oA1, lsA);
            attn_tile<false>(kf, qfB, vf, lo5, hi, oB0, oB1, lsB);
        } else if (t < jB) {
            attn_tile<false>(kf, qfB, vf, lo5, hi, oB0, oB1, lsB);
        } else if (t == jB) {
            attn_tile<true >(kf, qfB, vf, lo5, hi, oB0, oB1, lsB);
        }
        asm volatile("s_waitcnt lgkmcnt(0)" ::: "memory");
        __builtin_amdgcn_sched_barrier(0);
        __builtin_amdgcn_s_barrier();              // all waves done reading kv[buf]
        __builtin_amdgcn_sched_barrier(0);
        buf ^= 1;
    }

    int b = bh >> 4, h = bh & 15;
    float invA = 1.0f / xsum32(lsA);
    float invB = 1.0f / xsum32(lsB);
#pragma unroll
    for (int c = 0; c < 2; ++c) {
        int q0 = c ? q0B : q0A;
        const f32x16& o0 = c ? oB0 : oA0;
        const f32x16& o1 = c ? oB1 : oA1;
        float inv = c ? invB : invA;
        __hip_bfloat16* orow = O + ((long)b * SEQ + q0 + lo5) * DM + h * HD;
#pragma unroll
        for (int nd = 0; nd < 2; ++nd) {
#pragma unroll
            for (int rg = 0; rg < 4; ++rg) {
                ushort4 s4;
                float a0 = (nd ? o1[rg * 4 + 0] : o0[rg * 4 + 0]) * inv;
                float a1 = (nd ? o1[rg * 4 + 1] : o0[rg * 4 + 1]) * inv;
                float a2 = (nd ? o1[rg * 4 + 2] : o0[rg * 4 + 2]) * inv;
                float a3 = (nd ? o1[rg * 4 + 3] : o0[rg * 4 + 3]) * inv;
                s4.x = __bfloat16_as_ushort(__float2bfloat16(a0));
                s4.y = __bfloat16_as_ushort(__float2bfloat16(a1));
                s4.z = __bfloat16_as_ushort(__float2bfloat16(a2));
                s4.w = __bfloat16_as_ushort(__float2bfloat16(a3));
                *reinterpret_cast<ushort4*>(orow + nd * 32 + rg * 8 + hi * 4) = s4;
            }
        }
    }
}

extern "C" void kernel_launch(void* const* d_in, const int* in_sizes, int n_in,
                              void* d_out, int out_size, void* d_ws, size_t ws_size,
                              hipStream_t stream) {
    const float* x  = (const float*)d_in[0];
    const float* Wq = (const float*)d_in[1];
    const float* bq = (const float*)d_in[2];
    const float* Wk = (const float*)d_in[3];
    const float* bk = (const float*)d_in[4];
    const float* Wv = (const float*)d_in[5];
    const float* bv = (const float*)d_in[6];
    const float* Wp = (const float*)d_in[7];
    const float* bp = (const float*)d_in[8];
    float* out = (float*)d_out;

    char* ws = (char*)d_ws;
    const long XE = (long)NB * SEQ * DM;                 // 8,388,608
    const long QKV_ELEMS = (long)NB * NH * SEQ * HD;     // 8,388,608
    __hip_bfloat16* xb   = (__hip_bfloat16*)ws; ws += XE * 2;
    __hip_bfloat16* Qws  = (__hip_bfloat16*)ws; ws += QKV_ELEMS * 2;
    __hip_bfloat16* Kws  = (__hip_bfloat16*)ws; ws += QKV_ELEMS * 2;
    __hip_bfloat16* Vtws = (__hip_bfloat16*)ws; ws += QKV_ELEMS * 2;
    __hip_bfloat16* Ows  = (__hip_bfloat16*)ws; ws += QKV_ELEMS * 2;
    __hip_bfloat16* wqt  = (__hip_bfloat16*)ws; ws += (long)NH * DM * HD * 2;
    __hip_bfloat16* wkt  = (__hip_bfloat16*)ws; ws += (long)NH * DM * HD * 2;
    __hip_bfloat16* wvt  = (__hip_bfloat16*)ws; ws += (long)NH * DM * HD * 2;
    __hip_bfloat16* wpt  = (__hip_bfloat16*)ws; ws += (long)DM * DM * 2;

    prep<<<20480, 256, 0, stream>>>(x, Wq, Wk, Wv, Wp, xb, wqt, wkt, wvt, wpt);

    qkv_gemm<<<dim3(64, 24), 256, 0, stream>>>(
        xb, wqt, bq, bk, bv, Qws, Kws, Vtws);

    flash_attn<<<dim3(64, 8), 256, 0, stream>>>(Qws, Kws, Vtws, Ows);

    out_gemm<<<dim3(64, 8), 256, 0, stream>>>(Ows, wpt, bp, out);
}